// Round 7
// baseline (445.416 us; speedup 1.0000x reference)
//
#include <hip/hip_runtime.h>
#include <math.h>

#define D 256        // d_in == d_out == 256
#define TM 32        // target rows per block (1250 blocks, 8 rows per wave)
#define LN_EPS 1e-5f
#define SCAN_CHUNK 1024   // elements per block in scan kernels

// ---------------------------------------------------------------------------
// CSR build: histogram -> scan (2 kernels) -> reorder   (~10us total)
// ---------------------------------------------------------------------------
__global__ __launch_bounds__(256) void hist_kernel(
    const int* __restrict__ rows, int* __restrict__ cnt, int nnz)
{
    const int e = blockIdx.x * 256 + threadIdx.x;
    if (e < nnz) atomicAdd(&cnt[rows[e]], 1);
}

__global__ __launch_bounds__(256) void scan1_kernel(
    const int* __restrict__ cnt, int* __restrict__ row_ptr,
    int* __restrict__ partials, int n)
{
    const int tid = threadIdx.x;
    const int base = blockIdx.x * SCAN_CHUNK + tid * 4;
    int v[4];
#pragma unroll
    for (int q = 0; q < 4; q++) {
        const int i = base + q;
        v[q] = (i < n) ? cnt[i] : 0;
    }
    const int tsum = v[0] + v[1] + v[2] + v[3];

    const int lane = tid & 63;
    int s = tsum;
#pragma unroll
    for (int off = 1; off < 64; off <<= 1) {
        const int t = __shfl_up(s, off);
        if (lane >= off) s += t;
    }
    __shared__ int wtot[4];
    if (lane == 63) wtot[tid >> 6] = s;
    __syncthreads();
    const int w = tid >> 6;
    int woff = 0;
#pragma unroll
    for (int u = 0; u < 4; u++) if (u < w) woff += wtot[u];

    int run = woff + s - tsum;
#pragma unroll
    for (int q = 0; q < 4; q++) {
        const int i = base + q;
        if (i < n) row_ptr[i] = run;
        run += v[q];
    }
    if (tid == 255) partials[blockIdx.x] = woff + s;
}

// Merged scan2+scan3: each block wave-scans the (<=64) partials itself,
// then applies its exclusive prefix.
__global__ __launch_bounds__(256) void scan23_kernel(
    int* __restrict__ row_ptr, int* __restrict__ cursor,
    const int* __restrict__ partials, int n, int nnz, int nb)
{
    const int tid = threadIdx.x;
    __shared__ int s_add;
    if (tid < 64) {
        const int v = (tid < nb) ? partials[tid] : 0;
        int s = v;
#pragma unroll
        for (int off = 1; off < 64; off <<= 1) {
            const int u = __shfl_up(s, off);
            if (tid >= off) s += u;
        }
        if (tid == (int)blockIdx.x) s_add = s - v;   // exclusive prefix
    }
    __syncthreads();
    const int add = s_add;

    const int base = blockIdx.x * SCAN_CHUNK + tid * 4;
#pragma unroll
    for (int q = 0; q < 4; q++) {
        const int i = base + q;
        if (i < n) {
            const int rp = row_ptr[i] + add;
            row_ptr[i] = rp;
            cursor[i]  = rp;
        }
    }
    if (blockIdx.x == 0 && tid == 0) row_ptr[n] = nnz;
}

__global__ __launch_bounds__(256) void reorder_kernel(
    const int* __restrict__ rows, const int* __restrict__ cols,
    const float* __restrict__ vals, int* __restrict__ cursor,
    int* __restrict__ scol, float* __restrict__ sval, int nnz)
{
    const int e = blockIdx.x * 256 + threadIdx.x;
    if (e < nnz) {
        const int r = rows[e];
        const int pos = atomicAdd(&cursor[r], 1);
        scol[pos] = cols[e];
        sval[pos] = vals[e];
    }
}

// ---------------------------------------------------------------------------
// FUSED gather-SpMM + GEMM + bias + LayerNorm + GELU — BARRIER-FREE.
//
// Round-6 post-mortem: three different gather structures (MLP-4/occupancy-32,
// batch-8, asm-forced MLP-8) all land at 170-176us. VALUBusy 35% + HBM 13%
// with neither pipe saturated = phase ALTERNATION: all blocks gather in
// lockstep (VALU idle), hit __syncthreads, then GEMM in lockstep (memory
// idle). This round removes every barrier:
//   - each wave gathers its own 8 rows into its own quarter of As
//     (intra-wave LDS ordering only — compiler's lgkmcnt handles it),
//   - then immediately runs its own 8-row GEMM reading W straight from
//     L2 (256KB chip-resident; ~1.3GB aggregate re-read @ ~34TB/s L2,
//     overlapped) instead of barrier-staged Bs tiles,
//   - epilogue per wave: full-wave shfl reduction (lane owns 4 cols).
// Waves drift out of phase -> one wave's memory stalls overlap another's
// FMA bursts. Gather mechanics byte-identical to round 6 (proven).
// LDS 32KB (As only). n_tgt = 40000 = 1250*32 exactly -> no guards.
// ---------------------------------------------------------------------------
__global__ __launch_bounds__(256, 4) void fused_spmm_gemm_kernel(
    const float* __restrict__ x, const int* __restrict__ row_ptr,
    const int* __restrict__ scol, const float* __restrict__ sval,
    const float* __restrict__ Wm, const float* __restrict__ bias,
    const float* __restrict__ gamma, const float* __restrict__ beta,
    float* __restrict__ out)
{
    __shared__ float As[TM][D];        // 32 KB: gathered rows (fp32)

    const int tid  = threadIdx.x;
    const int wv   = tid >> 6;         // wave 0..3
    const int lane = tid & 63;
    const int r0   = blockIdx.x * TM;

    // ---- Phase 1: gather 8 rows (this wave's own) ----
    const int rbase = r0 + wv * 8;
    int rp = 0;
    if (lane < 9) rp = row_ptr[rbase + lane];   // rbase+8 <= n_tgt, valid
    const int rbeg = __shfl(rp, 0);
    const int rend = __shfl(rp, 8);

    // wave-scope metadata window [wbase, wbase+64)
    int wbase = rbeg;
    int   cidx = 0;
    float cval = 0.f;
    {
        const int tot = min(64, rend - wbase);
        if (lane < tot) {
            cidx = scol[wbase + lane];
            cval = sval[wbase + lane];
        }
    }

    for (int rr = 0; rr < 8; rr++) {
        const int beg = __shfl(rp, rr);
        const int end = __shfl(rp, rr + 1);

        float4 a0 = make_float4(0.f, 0.f, 0.f, 0.f);
        float4 a1 = a0, a2 = a0, a3 = a0;

        int e = beg;
        while (e < end) {
            if (e >= wbase + 64) {          // uniform: slide metadata window
                wbase = e;
                const int tot = min(64, rend - wbase);
                cidx = (lane < tot) ? scol[wbase + lane] : 0;
                cval = (lane < tot) ? sval[wbase + lane] : 0.f;
            }
            const int avail = min(end - e, wbase + 64 - e);
            const int bcnt  = min(8, avail);

            // broadcast 8 (col, val); pad slots clamp to slot e with v=0
            int   cc[8];
            float vv[8];
#pragma unroll
            for (int u = 0; u < 8; u++) {
                const int sl = (u < bcnt) ? (e + u - wbase) : (e - wbase);
                cc[u] = __shfl(cidx, sl);
                const float fv = __shfl(cval, sl);
                vv[u] = (u < bcnt) ? fv : 0.f;
            }

            // ---- asm-forced 8-deep batch: issue all, wait once, then FMA
            const float* p0 = x + (size_t)cc[0] * D + 4 * lane;
            const float* p1 = x + (size_t)cc[1] * D + 4 * lane;
            const float* p2 = x + (size_t)cc[2] * D + 4 * lane;
            const float* p3 = x + (size_t)cc[3] * D + 4 * lane;
            const float* p4 = x + (size_t)cc[4] * D + 4 * lane;
            const float* p5 = x + (size_t)cc[5] * D + 4 * lane;
            const float* p6 = x + (size_t)cc[6] * D + 4 * lane;
            const float* p7 = x + (size_t)cc[7] * D + 4 * lane;
            float4 x0, x1, x2, x3, x4, x5, x6, x7;
#define GLD(dst, ptr) \
    asm volatile("global_load_dwordx4 %0, %1, off" : "=v"(dst) : "v"(ptr))
            GLD(x0, p0); GLD(x1, p1); GLD(x2, p2); GLD(x3, p3);
            GLD(x4, p4); GLD(x5, p5); GLD(x6, p6); GLD(x7, p7);
#undef GLD
            asm volatile("s_waitcnt vmcnt(0)" ::: "memory");
            __builtin_amdgcn_sched_barrier(0);

            a0.x = fmaf(vv[0], x0.x, a0.x); a0.y = fmaf(vv[0], x0.y, a0.y);
            a0.z = fmaf(vv[0], x0.z, a0.z); a0.w = fmaf(vv[0], x0.w, a0.w);
            a1.x = fmaf(vv[1], x1.x, a1.x); a1.y = fmaf(vv[1], x1.y, a1.y);
            a1.z = fmaf(vv[1], x1.z, a1.z); a1.w = fmaf(vv[1], x1.w, a1.w);
            a2.x = fmaf(vv[2], x2.x, a2.x); a2.y = fmaf(vv[2], x2.y, a2.y);
            a2.z = fmaf(vv[2], x2.z, a2.z); a2.w = fmaf(vv[2], x2.w, a2.w);
            a3.x = fmaf(vv[3], x3.x, a3.x); a3.y = fmaf(vv[3], x3.y, a3.y);
            a3.z = fmaf(vv[3], x3.z, a3.z); a3.w = fmaf(vv[3], x3.w, a3.w);
            a0.x = fmaf(vv[4], x4.x, a0.x); a0.y = fmaf(vv[4], x4.y, a0.y);
            a0.z = fmaf(vv[4], x4.z, a0.z); a0.w = fmaf(vv[4], x4.w, a0.w);
            a1.x = fmaf(vv[5], x5.x, a1.x); a1.y = fmaf(vv[5], x5.y, a1.y);
            a1.z = fmaf(vv[5], x5.z, a1.z); a1.w = fmaf(vv[5], x5.w, a1.w);
            a2.x = fmaf(vv[6], x6.x, a2.x); a2.y = fmaf(vv[6], x6.y, a2.y);
            a2.z = fmaf(vv[6], x6.z, a2.z); a2.w = fmaf(vv[6], x6.w, a2.w);
            a3.x = fmaf(vv[7], x7.x, a3.x); a3.y = fmaf(vv[7], x7.y, a3.y);
            a3.z = fmaf(vv[7], x7.z, a3.z); a3.w = fmaf(vv[7], x7.w, a3.w);

            e += bcnt;
        }
        const float4 s = make_float4(a0.x + a1.x + a2.x + a3.x,
                                     a0.y + a1.y + a2.y + a3.y,
                                     a0.z + a1.z + a2.z + a3.z,
                                     a0.w + a1.w + a2.w + a3.w);
        *(float4*)&As[wv * 8 + rr][4 * lane] = s;
    }
    // NO __syncthreads: this wave reads only its own As rows below;
    // compiler orders the intra-wave LDS write->read via lgkmcnt.

    // ---- Phase 2: per-wave 8-row GEMM, W from L2 ----
    // lane owns output cols 4*lane..4*lane+3 for all 8 rows.
    float acc[8][4];
#pragma unroll
    for (int r = 0; r < 8; r++)
#pragma unroll
        for (int j = 0; j < 4; j++) acc[r][j] = 0.f;

#pragma unroll 2
    for (int kq = 0; kq < D / 4; kq++) {      // 64 k-quads
        const int k = kq * 4;
        const float4 w0 = *(const float4*)(Wm + (size_t)(k + 0) * D + 4 * lane);
        const float4 w1 = *(const float4*)(Wm + (size_t)(k + 1) * D + 4 * lane);
        const float4 w2 = *(const float4*)(Wm + (size_t)(k + 2) * D + 4 * lane);
        const float4 w3 = *(const float4*)(Wm + (size_t)(k + 3) * D + 4 * lane);
        float4 ar[8];
#pragma unroll
        for (int r = 0; r < 8; r++)
            ar[r] = *(const float4*)&As[wv * 8 + r][k];   // uniform: broadcast
#pragma unroll
        for (int r = 0; r < 8; r++) {
            acc[r][0] = fmaf(ar[r].x, w0.x, acc[r][0]);
            acc[r][1] = fmaf(ar[r].x, w0.y, acc[r][1]);
            acc[r][2] = fmaf(ar[r].x, w0.z, acc[r][2]);
            acc[r][3] = fmaf(ar[r].x, w0.w, acc[r][3]);
            acc[r][0] = fmaf(ar[r].y, w1.x, acc[r][0]);
            acc[r][1] = fmaf(ar[r].y, w1.y, acc[r][1]);
            acc[r][2] = fmaf(ar[r].y, w1.z, acc[r][2]);
            acc[r][3] = fmaf(ar[r].y, w1.w, acc[r][3]);
            acc[r][0] = fmaf(ar[r].z, w2.x, acc[r][0]);
            acc[r][1] = fmaf(ar[r].z, w2.y, acc[r][1]);
            acc[r][2] = fmaf(ar[r].z, w2.z, acc[r][2]);
            acc[r][3] = fmaf(ar[r].z, w2.w, acc[r][3]);
            acc[r][0] = fmaf(ar[r].w, w3.x, acc[r][0]);
            acc[r][1] = fmaf(ar[r].w, w3.y, acc[r][1]);
            acc[r][2] = fmaf(ar[r].w, w3.z, acc[r][2]);
            acc[r][3] = fmaf(ar[r].w, w3.w, acc[r][3]);
        }
    }

    // ---- epilogue: bias + LayerNorm (full-wave reduce) + exact GELU
    float gm[4], bt[4], bs[4];
#pragma unroll
    for (int j = 0; j < 4; j++) {
        const int c = 4 * lane + j;
        gm[j] = gamma[c]; bt[j] = beta[c]; bs[j] = bias[c];
    }

#pragma unroll
    for (int rr = 0; rr < 8; rr++) {
        float h[4];
        float s = 0.f, ss = 0.f;
#pragma unroll
        for (int j = 0; j < 4; j++) {
            h[j] = acc[rr][j] + bs[j];
            s += h[j]; ss += h[j] * h[j];
        }
#pragma unroll
        for (int off = 32; off > 0; off >>= 1) {
            s  += __shfl_xor(s,  off);
            ss += __shfl_xor(ss, off);
        }
        const float mean = s * (1.f / D);
        const float var  = ss * (1.f / D) - mean * mean;
        const float rstd = rsqrtf(var + LN_EPS);

        float y[4];
#pragma unroll
        for (int j = 0; j < 4; j++) {
            const float v = (h[j] - mean) * rstd * gm[j] + bt[j];
            y[j] = 0.5f * v * (1.f + erff(v * 0.70710678118654752f));
        }
        float* op = out + (size_t)(rbase + rr) * D;
        *(float4*)(op + 4 * lane) = make_float4(y[0], y[1], y[2], y[3]);
    }
}

// ---------------------------------------------------------------------------
extern "C" void kernel_launch(void* const* d_in, const int* in_sizes, int n_in,
                              void* d_out, int out_size, void* d_ws, size_t ws_size,
                              hipStream_t stream) {
    const float* x     = (const float*)d_in[0];
    const int*   rows  = (const int*)d_in[1];
    const int*   cols  = (const int*)d_in[2];
    const float* vals  = (const float*)d_in[3];
    const float* Wm    = (const float*)d_in[4];
    const float* bias  = (const float*)d_in[5];
    const float* gamma = (const float*)d_in[6];
    const float* beta  = (const float*)d_in[7];
    float* out = (float*)d_out;

    const int nnz   = in_sizes[1];
    const int n_tgt = out_size / D;          // 40000

    // workspace layout
    int* cnt      = (int*)d_ws;                         // [n_tgt]
    int* row_ptr  = cnt + n_tgt;                        // [n_tgt+1]
    int* cursor   = row_ptr + n_tgt + 1;                // [n_tgt]
    int* partials = cursor + n_tgt;                     // [64]
    int* scol     = partials + 64;                      // [nnz]
    float* sval   = (float*)(scol + nnz);               // [nnz]

    (void)hipMemsetAsync(cnt, 0, (size_t)n_tgt * sizeof(int), stream);

    const int eblocks = (nnz + 255) / 256;
    hist_kernel<<<eblocks, 256, 0, stream>>>(rows, cnt, nnz);

    const int sblocks = (n_tgt + SCAN_CHUNK - 1) / SCAN_CHUNK;   // 40
    scan1_kernel<<<sblocks, 256, 0, stream>>>(cnt, row_ptr, partials, n_tgt);
    scan23_kernel<<<sblocks, 256, 0, stream>>>(row_ptr, cursor, partials,
                                               n_tgt, nnz, sblocks);

    reorder_kernel<<<eblocks, 256, 0, stream>>>(rows, cols, vals, cursor,
                                                scol, sval, nnz);

    const int gblocks = n_tgt / TM;   // 1250
    fused_spmm_gemm_kernel<<<gblocks, 256, 0, stream>>>(
        x, row_ptr, scol, sval, Wm, bias, gamma, beta, out);
}